// Round 4
// baseline (10727.816 us; speedup 1.0000x reference)
//
#include <hip/hip_runtime.h>
#include <hip/hip_bf16.h>

typedef short bf16x8 __attribute__((ext_vector_type(8)));
typedef float f32x4 __attribute__((ext_vector_type(4)));

static constexpr int T_SEQ  = 512;
static constexpr int BATCH  = 64;
static constexpr int HID    = 512;
static constexpr int EMBD   = 256;
static constexpr int VOC    = 128;
static constexpr int NSLICE = 32;   // blocks per recurrence layer; 16 output rows each
static constexpr int FLAG_PAD = 64; // ints between per-chain flags (256B)

// ---- canonical bf16 arena element offsets (hi plane; lo plane at +ATOT) ----
static constexpr int AOFF_EMB  = 0;
static constexpr int AOFF_WXH0 = 32768;
static constexpr int AOFF_WHH0 = 163840;
static constexpr int AOFF_BH0  = 425984;
static constexpr int AOFF_WXH1 = 426496;
static constexpr int AOFF_WHH1 = 688640;
static constexpr int AOFF_BH1  = 950784;
static constexpr int AOFF_WHY  = 951296;
static constexpr int AOFF_BY   = 1016832;
static constexpr int ATOT      = 1016960;

// ---- ws byte offsets ----
static constexpr size_t OFF_FLAGS  = 0;                    // 8*FLAG_PAD ints
static constexpr size_t OFF_ARENA  = 4096;                 // 2*ATOT bf16 (hi,lo)
static constexpr size_t HPLANE_E   = (size_t)T_SEQ * BATCH * HID;   // 16,777,216 elems
static constexpr size_t HPLANE_B   = HPLANE_E * 2;                  // 33,554,432 B
static constexpr size_t OFF_H0HI   = 8 * 1024 * 1024;
static constexpr size_t OFF_H0LO   = OFF_H0HI + HPLANE_B;
static constexpr size_t OFF_H1HI   = OFF_H0LO + HPLANE_B;
static constexpr size_t OFF_H1LO   = OFF_H1HI + HPLANE_B;  // ends ~142.6 MB

__device__ __forceinline__ float bf2f(unsigned short u) {
  union { unsigned int i; float f; } c; c.i = (unsigned int)u << 16; return c.f;
}
__device__ __forceinline__ unsigned short f2bf(float f) {
  union { float f; unsigned int i; } c; c.f = f;
  unsigned int r = c.i + 0x7FFFu + ((c.i >> 16) & 1u);  // RNE
  return (unsigned short)(r >> 16);
}
__device__ __forceinline__ bf16x8 ldb(const unsigned short* p) {
  return *(const bf16x8*)p;
}

// fp32 params -> hi/lo bf16 arenas; zero flags.
__global__ __launch_bounds__(256) void canon_kernel(
    const float* p0, const float* p1, const float* p2, const float* p3,
    const float* p4, const float* p5, const float* p6, const float* p7,
    const float* p8, unsigned short* __restrict__ dst, int* __restrict__ flags) {
  if (blockIdx.x == 0)
    for (int i = threadIdx.x; i < 8 * FLAG_PAD; i += 256) flags[i] = 0;
  const float* srcs[9] = {p0, p1, p2, p3, p4, p5, p6, p7, p8};
  const int ns[9] = {32768, 131072, 262144, 512, 262144, 262144, 512, 65536, 128};
  for (int i = blockIdx.x * 256 + threadIdx.x; i < ATOT; i += gridDim.x * 256) {
    int off = i, s = 0;
    while (off >= ns[s]) { off -= ns[s]; ++s; }
    float v = srcs[s][off];
    unsigned short hi = f2bf(v);
    float d = v - bf2f(hi);            // exact
    dst[i]        = hi;
    dst[ATOT + i] = f2bf(d);
  }
}

// Persistent recurrence kernel. Grid = 32 blocks x 256 threads.
// Block g owns h rows [16g,16g+16); wave w owns batch chain [16w,16w+16).
// All operands hi/lo-split bf16; fp32 MFMA accumulate; effective ~2^-18 input
// precision via A_hi*B_hi + A_hi*B_lo + A_lo*B_hi.
template <int KIN, bool GATHER>
__global__ __launch_bounds__(256, 1) void rnn_layer_kernel(
    const int* __restrict__ x,
    const unsigned short* __restrict__ ain_hi,  // GATHER ? emb : h_in (T,B,HID)
    const unsigned short* __restrict__ ain_lo,
    const unsigned short* __restrict__ Wxh_hi,  // (HID,KIN)
    const unsigned short* __restrict__ Wxh_lo,
    const unsigned short* __restrict__ Whh_hi,  // (HID,HID)
    const unsigned short* __restrict__ Whh_lo,
    const float* __restrict__ bhf,              // (HID) fp32
    unsigned short* __restrict__ hout_hi,       // (T,B,HID)
    unsigned short* __restrict__ hout_lo,
    int* __restrict__ flags)
{
  const int g    = blockIdx.x;
  const int wv   = threadIdx.x >> 6;
  const int lane = threadIdx.x & 63;
  const int l15  = lane & 15;
  const int quad = lane >> 4;
  const int ns   = g * 16;
  const int bb   = wv * 16;
  constexpr int KCX = KIN / 32;

  // Register-resident weights, B-fragment layout:
  // B[k=quad*8+j][n=l15] = W[ns+l15][kc*32 + quad*8 + j]
  bf16x8 Bhh[16], Bhl[16];
#pragma unroll
  for (int kc = 0; kc < 16; ++kc) {
    Bhh[kc] = ldb(Whh_hi + (size_t)(ns + l15) * HID + kc * 32 + quad * 8);
    Bhl[kc] = ldb(Whh_lo + (size_t)(ns + l15) * HID + kc * 32 + quad * 8);
  }
  bf16x8 Bxh[KCX], Bxl[KCX];
#pragma unroll
  for (int kc = 0; kc < KCX; ++kc) {
    Bxh[kc] = ldb(Wxh_hi + (size_t)(ns + l15) * KIN + kc * 32 + quad * 8);
    Bxl[kc] = ldb(Wxh_lo + (size_t)(ns + l15) * KIN + kc * 32 + quad * 8);
  }
  const float bias = bhf[ns + l15];

  int* flag = flags + wv * FLAG_PAD;

  for (int t = 0; t < T_SEQ; ++t) {
    f32x4 acc[4];
    acc[0] = { bias, bias, bias, bias };
    acc[1] = acc[2] = acc[3] = f32x4{0.f, 0.f, 0.f, 0.f};

    // ---- input projection (independent of h_{t-1}; done BEFORE the flag wait)
    {
      const unsigned short *arow_hi, *arow_lo;
      if constexpr (GATHER) {
        const int idx = x[(bb + l15) * T_SEQ + t];
        arow_hi = ain_hi + (size_t)idx * EMBD + quad * 8;
        arow_lo = ain_lo + (size_t)idx * EMBD + quad * 8;
      } else {
        const size_t off = ((size_t)t * BATCH + bb + l15) * HID + quad * 8;
        arow_hi = ain_hi + off;
        arow_lo = ain_lo + off;
      }
#pragma unroll
      for (int c = 0; c < KCX; c += 8) {
        bf16x8 a[8];
#pragma unroll
        for (int i = 0; i < 8; ++i) a[i] = ldb(arow_hi + (c + i) * 32);
#pragma unroll
        for (int i = 0; i < 8; ++i)
          acc[i & 3] = __builtin_amdgcn_mfma_f32_16x16x32_bf16(a[i], Bxh[c + i], acc[i & 3], 0, 0, 0);
#pragma unroll
        for (int i = 0; i < 8; ++i)
          acc[i & 3] = __builtin_amdgcn_mfma_f32_16x16x32_bf16(a[i], Bxl[c + i], acc[i & 3], 0, 0, 0);
#pragma unroll
        for (int i = 0; i < 8; ++i) a[i] = ldb(arow_lo + (c + i) * 32);
#pragma unroll
        for (int i = 0; i < 8; ++i)
          acc[i & 3] = __builtin_amdgcn_mfma_f32_16x16x32_bf16(a[i], Bxh[c + i], acc[i & 3], 0, 0, 0);
      }
    }

    // ---- wait for h_{t-1} from all 32 blocks
    if (t > 0) {
      const int target = NSLICE * t;
      while (__hip_atomic_load(flag, __ATOMIC_RELAXED, __HIP_MEMORY_SCOPE_AGENT) < target)
        __builtin_amdgcn_s_sleep(2);
      __builtin_amdgcn_fence(__ATOMIC_ACQUIRE, "agent");

      // ---- recurrence: h_{t-1} @ W_hh^T, hi/lo compensated
      const size_t off = ((size_t)(t - 1) * BATCH + bb + l15) * HID + quad * 8;
#pragma unroll
      for (int c = 0; c < 16; c += 8) {
        bf16x8 a[8];
#pragma unroll
        for (int i = 0; i < 8; ++i) a[i] = ldb(hout_hi + off + (c + i) * 32);
#pragma unroll
        for (int i = 0; i < 8; ++i)
          acc[i & 3] = __builtin_amdgcn_mfma_f32_16x16x32_bf16(a[i], Bhh[c + i], acc[i & 3], 0, 0, 0);
#pragma unroll
        for (int i = 0; i < 8; ++i)
          acc[i & 3] = __builtin_amdgcn_mfma_f32_16x16x32_bf16(a[i], Bhl[c + i], acc[i & 3], 0, 0, 0);
#pragma unroll
        for (int i = 0; i < 8; ++i) a[i] = ldb(hout_lo + off + (c + i) * 32);
#pragma unroll
        for (int i = 0; i < 8; ++i)
          acc[i & 3] = __builtin_amdgcn_mfma_f32_16x16x32_bf16(a[i], Bhh[c + i], acc[i & 3], 0, 0, 0);
      }
    }

    // ---- epilogue: tanh fp32, hi/lo store. C/D: col=l15, row=quad*4+r.
    const size_t obase = ((size_t)t * BATCH + bb + quad * 4) * HID + ns + l15;
#pragma unroll
    for (int r = 0; r < 4; ++r) {
      float v = tanhf((acc[0][r] + acc[1][r]) + (acc[2][r] + acc[3][r]));
      unsigned short hi = f2bf(v);
      float d = v - bf2f(hi);
      hout_hi[obase + (size_t)r * HID] = hi;
      hout_lo[obase + (size_t)r * HID] = f2bf(d);
    }

    if (lane == 0)
      __hip_atomic_fetch_add(flag, 1, __ATOMIC_RELEASE, __HIP_MEMORY_SCOPE_AGENT);
  }
}

// logits[b][t][v] = h1[t][b][:] . W_hy[v][:] + b_y[v], fp32 out, hi/lo compensated.
__global__ __launch_bounds__(256, 1) void logits_kernel(
    const unsigned short* __restrict__ h1_hi, const unsigned short* __restrict__ h1_lo,
    const unsigned short* __restrict__ Why_hi, const unsigned short* __restrict__ Why_lo,
    const float* __restrict__ byf,
    float* __restrict__ out)                 // (B,T,VOC) fp32
{
  const int t    = blockIdx.x;
  const int wv   = threadIdx.x >> 6;
  const int lane = threadIdx.x & 63;
  const int l15  = lane & 15;
  const int quad = lane >> 4;
  const int bb   = wv * 16;

  f32x4 acc[8];
#pragma unroll
  for (int vt = 0; vt < 8; ++vt) {
    float bv = byf[vt * 16 + l15];
    acc[vt] = { bv, bv, bv, bv };
  }
  const size_t aoff = ((size_t)t * BATCH + bb + l15) * HID + quad * 8;
#pragma unroll
  for (int kc = 0; kc < 16; ++kc) {
    bf16x8 ah = ldb(h1_hi + aoff + kc * 32);
    bf16x8 al = ldb(h1_lo + aoff + kc * 32);
#pragma unroll
    for (int vt = 0; vt < 8; ++vt) {
      const size_t boff = (size_t)(vt * 16 + l15) * HID + kc * 32 + quad * 8;
      bf16x8 bh_ = ldb(Why_hi + boff);
      bf16x8 bl_ = ldb(Why_lo + boff);
      acc[vt] = __builtin_amdgcn_mfma_f32_16x16x32_bf16(ah, bh_, acc[vt], 0, 0, 0);
      acc[vt] = __builtin_amdgcn_mfma_f32_16x16x32_bf16(ah, bl_, acc[vt], 0, 0, 0);
      acc[vt] = __builtin_amdgcn_mfma_f32_16x16x32_bf16(al, bh_, acc[vt], 0, 0, 0);
    }
  }
#pragma unroll
  for (int vt = 0; vt < 8; ++vt) {
#pragma unroll
    for (int r = 0; r < 4; ++r) {
      const int b = bb + quad * 4 + r;
      const int v = vt * 16 + l15;
      out[((size_t)b * T_SEQ + t) * VOC + v] = acc[vt][r];
    }
  }
}

// h_last = h[T-1] reconstructed hi+lo, fp32 out.
__global__ void hlast_kernel(const unsigned short* __restrict__ h0_hi,
                             const unsigned short* __restrict__ h0_lo,
                             const unsigned short* __restrict__ h1_hi,
                             const unsigned short* __restrict__ h1_lo,
                             float* __restrict__ out)
{
  const size_t LOGITS = (size_t)BATCH * T_SEQ * VOC;
  const size_t HL = (size_t)BATCH * HID;
  const size_t base = (size_t)(T_SEQ - 1) * BATCH * HID;
  int tid = blockIdx.x * 256 + threadIdx.x;
  if (tid < (int)HL) {
    out[LOGITS + tid]      = bf2f(h0_hi[base + tid]) + bf2f(h0_lo[base + tid]);
    out[LOGITS + HL + tid] = bf2f(h1_hi[base + tid]) + bf2f(h1_lo[base + tid]);
  }
}

extern "C" void kernel_launch(void* const* d_in, const int* in_sizes, int n_in,
                              void* d_out, int out_size, void* d_ws, size_t ws_size,
                              hipStream_t stream) {
  const int* x = (const int*)d_in[0];
  float* out = (float*)d_out;

  char* ws = (char*)d_ws;
  int* flags = (int*)(ws + OFF_FLAGS);
  unsigned short* arena = (unsigned short*)(ws + OFF_ARENA);  // hi; lo at +ATOT
  unsigned short* h0hi = (unsigned short*)(ws + OFF_H0HI);
  unsigned short* h0lo = (unsigned short*)(ws + OFF_H0LO);
  unsigned short* h1hi = (unsigned short*)(ws + OFF_H1HI);
  unsigned short* h1lo = (unsigned short*)(ws + OFF_H1LO);

  canon_kernel<<<512, 256, 0, stream>>>(
      (const float*)d_in[1], (const float*)d_in[2], (const float*)d_in[3],
      (const float*)d_in[4], (const float*)d_in[5], (const float*)d_in[6],
      (const float*)d_in[7], (const float*)d_in[8], (const float*)d_in[9],
      arena, flags);

  rnn_layer_kernel<EMBD, true><<<NSLICE, 256, 0, stream>>>(
      x,
      arena + AOFF_EMB,  arena + ATOT + AOFF_EMB,
      arena + AOFF_WXH0, arena + ATOT + AOFF_WXH0,
      arena + AOFF_WHH0, arena + ATOT + AOFF_WHH0,
      (const float*)d_in[4],
      h0hi, h0lo, flags);

  rnn_layer_kernel<HID, false><<<NSLICE, 256, 0, stream>>>(
      nullptr,
      h0hi, h0lo,
      arena + AOFF_WXH1, arena + ATOT + AOFF_WXH1,
      arena + AOFF_WHH1, arena + ATOT + AOFF_WHH1,
      (const float*)d_in[7],
      h1hi, h1lo, flags + 4 * FLAG_PAD);

  logits_kernel<<<T_SEQ, 256, 0, stream>>>(
      h1hi, h1lo, arena + AOFF_WHY, arena + ATOT + AOFF_WHY,
      (const float*)d_in[9], out);

  hlast_kernel<<<(BATCH * HID + 255) / 256, 256, 0, stream>>>(
      h0hi, h0lo, h1hi, h1lo, out);
}

// Round 5
// 9276.514 us; speedup vs baseline: 1.1564x; 1.1564x over previous
//
#include <hip/hip_runtime.h>
#include <hip/hip_bf16.h>
#include <hip/hip_fp16.h>

typedef _Float16 f16x8 __attribute__((ext_vector_type(8)));
typedef float f32x4 __attribute__((ext_vector_type(4)));

static constexpr int T_SEQ = 512;
static constexpr int BATCH = 64;
static constexpr int HID   = 512;
static constexpr int EMBD  = 256;
static constexpr int VOC   = 128;

// ---- fp16 arena element offsets ----
static constexpr int AOFF_EMB  = 0;        // 128*256
static constexpr int AOFF_WXH0 = 32768;    // 512*256
static constexpr int AOFF_WHH0 = 163840;   // 512*512
static constexpr int AOFF_WXH1 = 425984;   // 512*512
static constexpr int AOFF_WHH1 = 688128;   // 512*512
static constexpr int AOFF_WHY  = 950272;   // 128*512
static constexpr int ATOT      = 1015808;

// ---- ws byte offsets ----
static constexpr size_t OFF_FLAGS = 0;                    // 16 counters * 64 ints
static constexpr size_t OFF_RING  = 4096;                 // 131072 u32 = 512 KB
static constexpr size_t OFF_ARENA = 532480;               // ATOT fp16 (~2 MB)
static constexpr size_t PLANE_B   = (size_t)T_SEQ * BATCH * HID * 2;  // 33,554,432
static constexpr size_t OFF_XW0   = 4u << 20;
static constexpr size_t OFF_XW1   = OFF_XW0 + PLANE_B;
static constexpr size_t OFF_H0P   = OFF_XW1 + PLANE_B;
static constexpr size_t OFF_H1P   = OFF_H0P + PLANE_B;    // ends ~138.4 MB

__device__ __forceinline__ unsigned short h2u(_Float16 h) {
  union { _Float16 h; unsigned short u; } c; c.h = h; return c.u;
}
__device__ __forceinline__ _Float16 u2h(unsigned short u) {
  union { unsigned short u; _Float16 h; } c; c.u = u; return c.h;
}

// fp32 params -> fp16 arena; zero flags.
__global__ __launch_bounds__(256) void canon_kernel(
    const float* p0, const float* p1, const float* p2, const float* p3,
    const float* p4, const float* p5,
    _Float16* __restrict__ dst, int* __restrict__ flags) {
  if (blockIdx.x == 0)
    for (int i = threadIdx.x; i < 16 * 64; i += 256) flags[i] = 0;
  const float* srcs[6] = {p0, p1, p2, p3, p4, p5};
  const int ns[6] = {32768, 131072, 262144, 262144, 262144, 65536};
  for (int i = blockIdx.x * 256 + threadIdx.x; i < ATOT; i += gridDim.x * 256) {
    int off = i, s = 0;
    while (off >= ns[s]) { off -= ns[s]; ++s; }
    dst[i] = (_Float16)srcs[s][off];
  }
}

// xw0[t*64+b][n] = emb[x[b,t]][:] . Wxh0[n][:] + bh0[n].  Grid (512, 8) x 256 thr.
__global__ __launch_bounds__(256) void xw0_kernel(
    const int* __restrict__ x, const _Float16* __restrict__ emb,
    const _Float16* __restrict__ Wxh, const float* __restrict__ bh,
    _Float16* __restrict__ xw) {
  __shared__ _Float16 Bs[64][264];   // 64 n-rows x 256 K, pad to 264
  const int m0 = blockIdx.x * 64, n0 = blockIdx.y * 64, tid = threadIdx.x;
#pragma unroll
  for (int rep = 0; rep < 8; ++rep) {
    int flat = rep * 256 + tid;      // 0..2047 chunks of 8
    int row = flat >> 5, c8 = flat & 31;
    *(f16x8*)&Bs[row][c8 * 8] = *(const f16x8*)&Wxh[(size_t)(n0 + row) * 256 + c8 * 8];
  }
  __syncthreads();
  const int wv = tid >> 6, lane = tid & 63, l15 = lane & 15, quad = lane >> 4;
  const int m = m0 + wv * 16 + l15, t = m >> 6, b = m & 63;
  const int idx = x[b * 512 + t];
  f32x4 acc[4];
#pragma unroll
  for (int nt = 0; nt < 4; ++nt) { float bv = bh[n0 + nt * 16 + l15]; acc[nt] = {bv, bv, bv, bv}; }
#pragma unroll
  for (int kc = 0; kc < 8; ++kc) {
    f16x8 a = *(const f16x8*)&emb[(size_t)idx * 256 + kc * 32 + quad * 8];
#pragma unroll
    for (int nt = 0; nt < 4; ++nt) {
      f16x8 bf = *(const f16x8*)&Bs[nt * 16 + l15][kc * 32 + quad * 8];
      acc[nt] = __builtin_amdgcn_mfma_f32_16x16x32_f16(a, bf, acc[nt], 0, 0, 0);
    }
  }
  const int mo = m0 + wv * 16 + quad * 4;
#pragma unroll
  for (int nt = 0; nt < 4; ++nt)
#pragma unroll
    for (int r = 0; r < 4; ++r)
      xw[(size_t)(mo + r) * 512 + n0 + nt * 16 + l15] = (_Float16)acc[nt][r];
}

// xw1[m][n] = h0[m][:] . Wxh1[n][:] + bh1[n].  Grid (512, 16) x 256 thr.
__global__ __launch_bounds__(256) void xw1_kernel(
    const _Float16* __restrict__ hin, const _Float16* __restrict__ Wxh,
    const float* __restrict__ bh, _Float16* __restrict__ xw) {
  __shared__ _Float16 Bs[32][520];   // 32 n-rows x 512 K
  const int m0 = blockIdx.x * 64, n0 = blockIdx.y * 32, tid = threadIdx.x;
#pragma unroll
  for (int rep = 0; rep < 8; ++rep) {
    int flat = rep * 256 + tid;      // 2048 chunks of 8
    int row = flat >> 6, c8 = flat & 63;
    *(f16x8*)&Bs[row][c8 * 8] = *(const f16x8*)&Wxh[(size_t)(n0 + row) * 512 + c8 * 8];
  }
  __syncthreads();
  const int wv = tid >> 6, lane = tid & 63, l15 = lane & 15, quad = lane >> 4;
  const int m = m0 + wv * 16 + l15;
  f32x4 acc[2];
#pragma unroll
  for (int nt = 0; nt < 2; ++nt) { float bv = bh[n0 + nt * 16 + l15]; acc[nt] = {bv, bv, bv, bv}; }
#pragma unroll
  for (int kc = 0; kc < 16; ++kc) {
    f16x8 a = *(const f16x8*)&hin[(size_t)m * 512 + kc * 32 + quad * 8];
#pragma unroll
    for (int nt = 0; nt < 2; ++nt) {
      f16x8 bf = *(const f16x8*)&Bs[nt * 16 + l15][kc * 32 + quad * 8];
      acc[nt] = __builtin_amdgcn_mfma_f32_16x16x32_f16(a, bf, acc[nt], 0, 0, 0);
    }
  }
  const int mo = m0 + wv * 16 + quad * 4;
#pragma unroll
  for (int nt = 0; nt < 2; ++nt)
#pragma unroll
    for (int r = 0; r < 4; ++r)
      xw[(size_t)(mo + r) * 512 + n0 + nt * 16 + l15] = (_Float16)acc[nt][r];
}

// Paired recurrence. Grid = 16 blocks x 512 thr; active: bid 0..3 (half 0) and
// 8..11 (half 1) -> pair {g, g+8} co-locates on one XCD under round-robin
// (speed heuristic only). Block holds W_hh rows [half*256, +256) in registers
// (2 tiles x 16 kc x 4 VGPR = 128/wave). h halves exchanged per step via
// relaxed device-scope atomic u32s in a 4-slot ring (pair is lockstep +-1:
// writer reuses slot t at t+4 only after partner flag >= t+3, i.e. partner
// consumed slot t at its step t+1). No cache-wide fences anywhere.
__global__ __launch_bounds__(512, 2) void rnn_pair_kernel(
    const _Float16* __restrict__ Whh, const _Float16* __restrict__ xw,
    _Float16* __restrict__ hplain, unsigned int* __restrict__ ring,
    int* __restrict__ flags) {
  const int bid = blockIdx.x;
  int g, half;
  if (bid < 4)                     { g = bid;     half = 0; }
  else if (bid >= 8 && bid < 12)   { g = bid - 8; half = 1; }
  else return;

  const int tid = threadIdx.x, wv = tid >> 6, lane = tid & 63;
  const int l15 = lane & 15, quad = lane >> 4;
  const int bb = g * 16;
  const int n0 = half * 256 + wv * 32;     // this wave's first output col

  __shared__ _Float16 hbuf[2][16][520];    // [buf][batch][K], pad 520 (2-way free)

  f16x8 Bw[2][16];                         // register-resident W_hh slice
#pragma unroll
  for (int tile = 0; tile < 2; ++tile)
#pragma unroll
    for (int kc = 0; kc < 16; ++kc)
      Bw[tile][kc] = *(const f16x8*)&Whh[(size_t)(n0 + tile * 16 + l15) * 512 + kc * 32 + quad * 8];

  int* myflag = flags + (g * 2 + half) * 64;
  int* pflag  = flags + (g * 2 + (1 - half)) * 64;
  unsigned int* myring = ring + (size_t)(g * 2 + half) * 4 * 2048;
  unsigned int* pring  = ring + (size_t)(g * 2 + (1 - half)) * 4 * 2048;
  const int kc_lo = half ? 8 : 0;          // K chunks this block produced
  const int kc_ro = half ? 0 : 8;          // K chunks from partner

  for (int t = 0; t < T_SEQ; ++t) {
    f32x4 acc[2];
#pragma unroll
    for (int tile = 0; tile < 2; ++tile)
#pragma unroll
      for (int r = 0; r < 4; ++r)
        acc[tile][r] = (float)xw[(size_t)(t * 64 + bb + quad * 4 + r) * 512 + n0 + tile * 16 + l15];

    if (t > 0) {
      const int p = (t - 1) & 1;
      // local-K MFMAs before waiting (own half of h_{t-1} is in LDS already)
#pragma unroll
      for (int k = 0; k < 8; ++k) {
        const int kc = kc_lo + k;
        f16x8 a = *(const f16x8*)&hbuf[p][l15][kc * 32 + quad * 8];
        acc[0] = __builtin_amdgcn_mfma_f32_16x16x32_f16(a, Bw[0][kc], acc[0], 0, 0, 0);
        acc[1] = __builtin_amdgcn_mfma_f32_16x16x32_f16(a, Bw[1][kc], acc[1], 0, 0, 0);
      }
      // wait for partner's h_{t-1}
      while (__hip_atomic_load(pflag, __ATOMIC_RELAXED, __HIP_MEMORY_SCOPE_AGENT) < t)
        __builtin_amdgcn_s_sleep(1);
      __atomic_signal_fence(__ATOMIC_ACQUIRE);
      // fetch partner half (4 u32 / thread, L3-coherent loads), unpack to LDS
      unsigned int* src = pring + (size_t)((t - 1) & 3) * 2048 + tid * 4;
      unsigned int v0 = __hip_atomic_load(src + 0, __ATOMIC_RELAXED, __HIP_MEMORY_SCOPE_AGENT);
      unsigned int v1 = __hip_atomic_load(src + 1, __ATOMIC_RELAXED, __HIP_MEMORY_SCOPE_AGENT);
      unsigned int v2 = __hip_atomic_load(src + 2, __ATOMIC_RELAXED, __HIP_MEMORY_SCOPE_AGENT);
      unsigned int v3 = __hip_atomic_load(src + 3, __ATOMIC_RELAXED, __HIP_MEMORY_SCOPE_AGENT);
      const int c = tid >> 1, bp0 = (tid & 1) * 4;
      const int kcol = (1 - half) * 256 + c;
      unsigned int vv[4] = {v0, v1, v2, v3};
#pragma unroll
      for (int i = 0; i < 4; ++i) {
        int b = (bp0 + i) * 2;
        hbuf[p][b][kcol]     = u2h((unsigned short)(vv[i] & 0xFFFFu));
        hbuf[p][b + 1][kcol] = u2h((unsigned short)(vv[i] >> 16));
      }
      __syncthreads();
      // remote-K MFMAs
#pragma unroll
      for (int k = 0; k < 8; ++k) {
        const int kc = kc_ro + k;
        f16x8 a = *(const f16x8*)&hbuf[p][l15][kc * 32 + quad * 8];
        acc[0] = __builtin_amdgcn_mfma_f32_16x16x32_f16(a, Bw[0][kc], acc[0], 0, 0, 0);
        acc[1] = __builtin_amdgcn_mfma_f32_16x16x32_f16(a, Bw[1][kc], acc[1], 0, 0, 0);
      }
    }

    // epilogue: tanh (fp32), write LDS(next) + plain global + exchange ring
    const int pn = t & 1;
    _Float16 hv[8];
#pragma unroll
    for (int tile = 0; tile < 2; ++tile)
#pragma unroll
      for (int r = 0; r < 4; ++r)
        hv[tile * 4 + r] = (_Float16)tanhf(acc[tile][r]);
#pragma unroll
    for (int tile = 0; tile < 2; ++tile)
#pragma unroll
      for (int r = 0; r < 4; ++r) {
        hbuf[pn][quad * 4 + r][n0 + tile * 16 + l15] = hv[tile * 4 + r];
        hplain[(size_t)(t * 64 + bb + quad * 4 + r) * 512 + n0 + tile * 16 + l15] = hv[tile * 4 + r];
      }
    unsigned int* dstr = myring + (size_t)(t & 3) * 2048;
#pragma unroll
    for (int tile = 0; tile < 2; ++tile)
#pragma unroll
      for (int rp = 0; rp < 2; ++rp) {
        unsigned int pk = ((unsigned int)h2u(hv[tile * 4 + rp * 2 + 1]) << 16) |
                          (unsigned int)h2u(hv[tile * 4 + rp * 2]);
        int idxu = (wv * 32 + tile * 16 + l15) * 8 + quad * 2 + rp;
        __hip_atomic_store(dstr + idxu, pk, __ATOMIC_RELAXED, __HIP_MEMORY_SCOPE_AGENT);
      }
    __syncthreads();   // drains every wave's vmcnt before the post
    if (tid == 0)
      __hip_atomic_store(myflag, t + 1, __ATOMIC_RELEASE, __HIP_MEMORY_SCOPE_AGENT);
  }
}

// logits[b][t][v] = h1[t*64+b][:] . Why[v][:] + by[v].  Grid 512 x 256 thr.
__global__ __launch_bounds__(256) void logits_kernel(
    const _Float16* __restrict__ h1, const _Float16* __restrict__ Why,
    const float* __restrict__ by, float* __restrict__ out) {
  const int t = blockIdx.x;
  const int wv = threadIdx.x >> 6, lane = threadIdx.x & 63;
  const int l15 = lane & 15, quad = lane >> 4, bb = wv * 16;
  f32x4 acc[8];
#pragma unroll
  for (int vt = 0; vt < 8; ++vt) { float bv = by[vt * 16 + l15]; acc[vt] = {bv, bv, bv, bv}; }
#pragma unroll
  for (int kc = 0; kc < 16; ++kc) {
    f16x8 a = *(const f16x8*)&h1[(size_t)(t * 64 + bb + l15) * 512 + kc * 32 + quad * 8];
#pragma unroll
    for (int vt = 0; vt < 8; ++vt) {
      f16x8 b = *(const f16x8*)&Why[(size_t)(vt * 16 + l15) * 512 + kc * 32 + quad * 8];
      acc[vt] = __builtin_amdgcn_mfma_f32_16x16x32_f16(a, b, acc[vt], 0, 0, 0);
    }
  }
#pragma unroll
  for (int vt = 0; vt < 8; ++vt)
#pragma unroll
    for (int r = 0; r < 4; ++r)
      out[((size_t)(bb + quad * 4 + r) * 512 + t) * 128 + vt * 16 + l15] = acc[vt][r];
}

__global__ void hlast_kernel(const _Float16* __restrict__ h0,
                             const _Float16* __restrict__ h1,
                             float* __restrict__ out) {
  const size_t LOG = (size_t)BATCH * T_SEQ * VOC;
  const size_t HL = (size_t)BATCH * HID;
  const size_t base = (size_t)(T_SEQ - 1) * BATCH * HID;
  int tid = blockIdx.x * 256 + threadIdx.x;
  if (tid < (int)HL) {
    out[LOG + tid]      = (float)h0[base + tid];
    out[LOG + HL + tid] = (float)h1[base + tid];
  }
}

extern "C" void kernel_launch(void* const* d_in, const int* in_sizes, int n_in,
                              void* d_out, int out_size, void* d_ws, size_t ws_size,
                              hipStream_t stream) {
  const int* x = (const int*)d_in[0];
  float* out = (float*)d_out;
  char* ws = (char*)d_ws;
  int* flags = (int*)(ws + OFF_FLAGS);
  unsigned int* ring = (unsigned int*)(ws + OFF_RING);   // 2 layers x 65536 u32
  _Float16* arena = (_Float16*)(ws + OFF_ARENA);
  _Float16* xw0 = (_Float16*)(ws + OFF_XW0);
  _Float16* xw1 = (_Float16*)(ws + OFF_XW1);
  _Float16* h0p = (_Float16*)(ws + OFF_H0P);
  _Float16* h1p = (_Float16*)(ws + OFF_H1P);

  canon_kernel<<<512, 256, 0, stream>>>(
      (const float*)d_in[1], (const float*)d_in[2], (const float*)d_in[3],
      (const float*)d_in[5], (const float*)d_in[6], (const float*)d_in[8],
      arena, flags);

  xw0_kernel<<<dim3(512, 8), 256, 0, stream>>>(
      x, arena + AOFF_EMB, arena + AOFF_WXH0, (const float*)d_in[4], xw0);

  rnn_pair_kernel<<<16, 512, 0, stream>>>(
      arena + AOFF_WHH0, xw0, h0p, ring, flags);

  xw1_kernel<<<dim3(512, 16), 256, 0, stream>>>(
      h0p, arena + AOFF_WXH1, (const float*)d_in[7], xw1);

  rnn_pair_kernel<<<16, 512, 0, stream>>>(
      arena + AOFF_WHH1, xw1, h1p, ring + 65536, flags + 8 * 64);

  logits_kernel<<<512, 256, 0, stream>>>(
      h1p, arena + AOFF_WHY, (const float*)d_in[9], out);

  hlast_kernel<<<(BATCH * HID + 255) / 256, 256, 0, stream>>>(h0p, h1p, out);
}

// Round 6
// 4780.927 us; speedup vs baseline: 2.2439x; 1.9403x over previous
//
#include <hip/hip_runtime.h>
#include <hip/hip_fp16.h>

typedef _Float16 f16x8 __attribute__((ext_vector_type(8)));
typedef float f32x4 __attribute__((ext_vector_type(4)));
typedef unsigned int u32x4 __attribute__((ext_vector_type(4)));
typedef unsigned int u32x2 __attribute__((ext_vector_type(2)));

static constexpr int T_SEQ = 512;
static constexpr int BATCH = 64;
static constexpr int HID   = 512;
static constexpr int VOC   = 128;

// ---- fp16 arena element offsets ----
static constexpr int AOFF_EMB  = 0;        // 128*256
static constexpr int AOFF_WXH0 = 32768;    // 512*256
static constexpr int AOFF_WHH0 = 163840;   // 512*512
static constexpr int AOFF_WXH1 = 425984;   // 512*512
static constexpr int AOFF_WHH1 = 688128;   // 512*512
static constexpr int AOFF_WHY  = 950272;   // 128*512
static constexpr int ATOT      = 1015808;

// ---- ws byte offsets ----
static constexpr size_t OFF_ARENA = 4096;
static constexpr size_t PLANE_B   = (size_t)T_SEQ * BATCH * HID * 2;  // 32 MB
static constexpr size_t OFF_XW0   = 4u << 20;           // xwf layer0 [t][n][b]
static constexpr size_t OFF_XW1   = OFF_XW0 + PLANE_B;  // xwf layer1
static constexpr size_t OFF_H0P   = OFF_XW1 + PLANE_B;  // h0 [t*64+b][n]
static constexpr size_t OFF_H1P   = OFF_H0P + PLANE_B;  // ends ~132 MB

__device__ __forceinline__ unsigned short h2u(_Float16 h) {
  union { _Float16 h; unsigned short u; } c; c.h = h; return c.u;
}
__device__ __forceinline__ _Float16 u2h(unsigned short u) {
  union { unsigned short u; _Float16 h; } c; c.u = u; return c.h;
}
// fast tanh: 1 - 2/(e^{2x}+1) via v_exp_f32 + v_rcp_f32 (~1e-7 rel; tanh-range safe)
__device__ __forceinline__ float fast_tanh(float x) {
  float e = __expf(2.0f * x);
  return 1.0f - 2.0f * __builtin_amdgcn_rcpf(e + 1.0f);
}

// fp32 params -> fp16 arena.
__global__ __launch_bounds__(256) void canon_kernel(
    const float* p0, const float* p1, const float* p2, const float* p3,
    const float* p4, const float* p5, _Float16* __restrict__ dst) {
  const float* srcs[6] = {p0, p1, p2, p3, p4, p5};
  const int ns[6] = {32768, 131072, 262144, 262144, 262144, 65536};
  for (int i = blockIdx.x * 256 + threadIdx.x; i < ATOT; i += gridDim.x * 256) {
    int off = i, s = 0;
    while (off >= ns[s]) { off -= ns[s]; ++s; }
    dst[i] = (_Float16)srcs[s][off];
  }
}

// xwf0[t][n][b] = emb[x[b,t]][:] . Wxh0[n][:] + bh0[n].  Grid (512, 8) x 256.
__global__ __launch_bounds__(256) void xw0_kernel(
    const int* __restrict__ x, const _Float16* __restrict__ emb,
    const _Float16* __restrict__ Wxh, const float* __restrict__ bh,
    _Float16* __restrict__ xwf) {
  __shared__ _Float16 Bs[64][264];
  const int t = blockIdx.x, n0 = blockIdx.y * 64, tid = threadIdx.x;
#pragma unroll
  for (int rep = 0; rep < 8; ++rep) {
    int flat = rep * 256 + tid;
    int row = flat >> 5, c8 = flat & 31;
    *(f16x8*)&Bs[row][c8 * 8] = *(const f16x8*)&Wxh[(size_t)(n0 + row) * 256 + c8 * 8];
  }
  __syncthreads();
  const int wv = tid >> 6, lane = tid & 63, l15 = lane & 15, quad = lane >> 4;
  const int b = wv * 16 + l15;
  const int idx = x[b * 512 + t];
  f32x4 acc[4];
#pragma unroll
  for (int nt = 0; nt < 4; ++nt) { float bv = bh[n0 + nt * 16 + l15]; acc[nt] = {bv, bv, bv, bv}; }
#pragma unroll
  for (int kc = 0; kc < 8; ++kc) {
    f16x8 a = *(const f16x8*)&emb[(size_t)idx * 256 + kc * 32 + quad * 8];
#pragma unroll
    for (int nt = 0; nt < 4; ++nt) {
      f16x8 bf = *(const f16x8*)&Bs[nt * 16 + l15][kc * 32 + quad * 8];
      acc[nt] = __builtin_amdgcn_mfma_f32_16x16x32_f16(a, bf, acc[nt], 0, 0, 0);
    }
  }
  // C-layout: n = n0+nt*16+l15 (col), b-row = wv*16+quad*4+r. Pack 4 r as b64.
#pragma unroll
  for (int nt = 0; nt < 4; ++nt) {
    unsigned int lo = (unsigned int)h2u((_Float16)acc[nt][0]) |
                      ((unsigned int)h2u((_Float16)acc[nt][1]) << 16);
    unsigned int hi = (unsigned int)h2u((_Float16)acc[nt][2]) |
                      ((unsigned int)h2u((_Float16)acc[nt][3]) << 16);
    u32x2 pk = {lo, hi};
    *(u32x2*)&xwf[(size_t)t * 32768 + (size_t)(n0 + nt * 16 + l15) * 64 + wv * 16 + quad * 4] = pk;
  }
}

// xwf1[t][n][b] = h0[t*64+b][:] . Wxh1[n][:] + bh1[n].  Grid (512, 16) x 256.
__global__ __launch_bounds__(256) void xw1_kernel(
    const _Float16* __restrict__ hin, const _Float16* __restrict__ Wxh,
    const float* __restrict__ bh, _Float16* __restrict__ xwf) {
  __shared__ _Float16 Bs[32][520];
  const int t = blockIdx.x, n0 = blockIdx.y * 32, tid = threadIdx.x;
#pragma unroll
  for (int rep = 0; rep < 8; ++rep) {
    int flat = rep * 256 + tid;
    int row = flat >> 6, c8 = flat & 63;
    *(f16x8*)&Bs[row][c8 * 8] = *(const f16x8*)&Wxh[(size_t)(n0 + row) * 512 + c8 * 8];
  }
  __syncthreads();
  const int wv = tid >> 6, lane = tid & 63, l15 = lane & 15, quad = lane >> 4;
  const int m = t * 64 + wv * 16 + l15;
  f32x4 acc[2];
#pragma unroll
  for (int nt = 0; nt < 2; ++nt) { float bv = bh[n0 + nt * 16 + l15]; acc[nt] = {bv, bv, bv, bv}; }
#pragma unroll
  for (int kc = 0; kc < 16; ++kc) {
    f16x8 a = *(const f16x8*)&hin[(size_t)m * 512 + kc * 32 + quad * 8];
#pragma unroll
    for (int nt = 0; nt < 2; ++nt) {
      f16x8 bf = *(const f16x8*)&Bs[nt * 16 + l15][kc * 32 + quad * 8];
      acc[nt] = __builtin_amdgcn_mfma_f32_16x16x32_f16(a, bf, acc[nt], 0, 0, 0);
    }
  }
#pragma unroll
  for (int nt = 0; nt < 2; ++nt) {
    unsigned int lo = (unsigned int)h2u((_Float16)acc[nt][0]) |
                      ((unsigned int)h2u((_Float16)acc[nt][1]) << 16);
    unsigned int hi = (unsigned int)h2u((_Float16)acc[nt][2]) |
                      ((unsigned int)h2u((_Float16)acc[nt][3]) << 16);
    u32x2 pk = {lo, hi};
    *(u32x2*)&xwf[(size_t)t * 32768 + (size_t)(n0 + nt * 16 + l15) * 64 + wv * 16 + quad * 4] = pk;
  }
}

// Sync-free recurrence: grid = 4 blocks x 512 thr. Block g owns batches
// [16g,16g+16) END-TO-END: full 512x512 W_hh register-resident across 8 waves
// (wave w -> output cols [64w,64w+64), 256 VGPR, pinned via no-op asm so the
// __syncthreads fence can't force re-loads). h_t in LDS double buffer.
// NO atomics, NO fences, ONE barrier per step.
__global__ __launch_bounds__(512, 1) void rnn_seq_kernel(
    const _Float16* __restrict__ Whh,   // (512 n, 512 k)
    const _Float16* __restrict__ xwf,   // [t][n][b] fragment layout
    _Float16* __restrict__ hplain)      // [t*64+b][n]
{
  const int g = blockIdx.x;
  const int tid = threadIdx.x, wv = tid >> 6, lane = tid & 63;
  const int l15 = lane & 15, quad = lane >> 4;
  const int bb = g * 16;
  const int n0 = wv * 64;

  __shared__ _Float16 hbuf[2][16][520];

  // Register-resident weights: B[k=quad*8+j][n=l15] = Whh[n0+tile*16+l15][kc*32+quad*8+j]
  u32x4 Bw[4][16];
#pragma unroll
  for (int tile = 0; tile < 4; ++tile)
#pragma unroll
    for (int kc = 0; kc < 16; ++kc)
      Bw[tile][kc] = *(const u32x4*)&Whh[(size_t)(n0 + tile * 16 + l15) * 512 + kc * 32 + quad * 8];
  // Pin: value becomes asm-opaque -> cannot be rematerialized into the loop.
#pragma unroll
  for (int tile = 0; tile < 4; ++tile)
#pragma unroll
    for (int kc = 0; kc < 16; ++kc)
      asm volatile("" : "+v"(Bw[tile][kc]));

  // xw prefetch for t=0 (4 x 8B loads/lane)
  const _Float16* xwb = xwf + (size_t)(n0 + l15) * 64 + bb + quad * 4;
  u32x2 pf[4];
#pragma unroll
  for (int tile = 0; tile < 4; ++tile)
    pf[tile] = *(const u32x2*)(xwb + (size_t)tile * 16 * 64);

  for (int t = 0; t < T_SEQ; ++t) {
    f32x4 acc[4];
#pragma unroll
    for (int tile = 0; tile < 4; ++tile) {
      u32x2 p = pf[tile];
      acc[tile][0] = (float)u2h((unsigned short)(p.x & 0xFFFFu));
      acc[tile][1] = (float)u2h((unsigned short)(p.x >> 16));
      acc[tile][2] = (float)u2h((unsigned short)(p.y & 0xFFFFu));
      acc[tile][3] = (float)u2h((unsigned short)(p.y >> 16));
    }
    if (t + 1 < T_SEQ) {
      const _Float16* nx = xwb + (size_t)(t + 1) * 32768;
#pragma unroll
      for (int tile = 0; tile < 4; ++tile)
        pf[tile] = *(const u32x2*)(nx + (size_t)tile * 16 * 64);
    }

    if (t > 0) {
      const int p = (t - 1) & 1;
#pragma unroll
      for (int kc = 0; kc < 16; ++kc) {
        f16x8 a = *(const f16x8*)&hbuf[p][l15][kc * 32 + quad * 8];
#pragma unroll
        for (int tile = 0; tile < 4; ++tile)
          acc[tile] = __builtin_amdgcn_mfma_f32_16x16x32_f16(
              a, __builtin_bit_cast(f16x8, Bw[tile][kc]), acc[tile], 0, 0, 0);
      }
    }

    // epilogue: tanh, write LDS (next buf) + global (fire-and-forget)
    const int pn = t & 1;
    _Float16* hrow = hplain + (size_t)(t * 64 + bb + quad * 4) * 512 + n0 + l15;
#pragma unroll
    for (int tile = 0; tile < 4; ++tile)
#pragma unroll
      for (int r = 0; r < 4; ++r) {
        _Float16 hh = (_Float16)fast_tanh(acc[tile][r]);
        hbuf[pn][quad * 4 + r][n0 + tile * 16 + l15] = hh;
        hrow[(size_t)r * 512 + tile * 16] = hh;
      }
    __syncthreads();
  }
}

// logits[b][t][v] = h1[t*64+b][:] . Why[v][:] + by[v].  Grid 512 x 256.
__global__ __launch_bounds__(256) void logits_kernel(
    const _Float16* __restrict__ h1, const _Float16* __restrict__ Why,
    const float* __restrict__ by, float* __restrict__ out) {
  const int t = blockIdx.x;
  const int wv = threadIdx.x >> 6, lane = threadIdx.x & 63;
  const int l15 = lane & 15, quad = lane >> 4, bb = wv * 16;
  f32x4 acc[8];
#pragma unroll
  for (int vt = 0; vt < 8; ++vt) { float bv = by[vt * 16 + l15]; acc[vt] = {bv, bv, bv, bv}; }
#pragma unroll
  for (int kc = 0; kc < 16; ++kc) {
    f16x8 a = *(const f16x8*)&h1[(size_t)(t * 64 + bb + l15) * 512 + kc * 32 + quad * 8];
#pragma unroll
    for (int vt = 0; vt < 8; ++vt) {
      f16x8 b = *(const f16x8*)&Why[(size_t)(vt * 16 + l15) * 512 + kc * 32 + quad * 8];
      acc[vt] = __builtin_amdgcn_mfma_f32_16x16x32_f16(a, b, acc[vt], 0, 0, 0);
    }
  }
#pragma unroll
  for (int vt = 0; vt < 8; ++vt)
#pragma unroll
    for (int r = 0; r < 4; ++r)
      out[((size_t)(bb + quad * 4 + r) * 512 + t) * 128 + vt * 16 + l15] = acc[vt][r];
}

__global__ void hlast_kernel(const _Float16* __restrict__ h0,
                             const _Float16* __restrict__ h1,
                             float* __restrict__ out) {
  const size_t LOG = (size_t)BATCH * T_SEQ * VOC;
  const size_t HL = (size_t)BATCH * HID;
  const size_t base = (size_t)(T_SEQ - 1) * BATCH * HID;
  int tid = blockIdx.x * 256 + threadIdx.x;
  if (tid < (int)HL) {
    out[LOG + tid]      = (float)h0[base + tid];
    out[LOG + HL + tid] = (float)h1[base + tid];
  }
}

extern "C" void kernel_launch(void* const* d_in, const int* in_sizes, int n_in,
                              void* d_out, int out_size, void* d_ws, size_t ws_size,
                              hipStream_t stream) {
  const int* x = (const int*)d_in[0];
  float* out = (float*)d_out;
  char* ws = (char*)d_ws;
  _Float16* arena = (_Float16*)(ws + OFF_ARENA);
  _Float16* xw0f = (_Float16*)(ws + OFF_XW0);
  _Float16* xw1f = (_Float16*)(ws + OFF_XW1);
  _Float16* h0p  = (_Float16*)(ws + OFF_H0P);
  _Float16* h1p  = (_Float16*)(ws + OFF_H1P);

  canon_kernel<<<512, 256, 0, stream>>>(
      (const float*)d_in[1], (const float*)d_in[2], (const float*)d_in[3],
      (const float*)d_in[5], (const float*)d_in[6], (const float*)d_in[8], arena);

  xw0_kernel<<<dim3(512, 8), 256, 0, stream>>>(
      x, arena + AOFF_EMB, arena + AOFF_WXH0, (const float*)d_in[4], xw0f);

  rnn_seq_kernel<<<4, 512, 0, stream>>>(arena + AOFF_WHH0, xw0f, h0p);

  xw1_kernel<<<dim3(512, 16), 256, 0, stream>>>(
      h0p, arena + AOFF_WXH1, (const float*)d_in[7], xw1f);

  rnn_seq_kernel<<<4, 512, 0, stream>>>(arena + AOFF_WHH1, xw1f, h1p);

  logits_kernel<<<512, 256, 0, stream>>>(
      h1p, arena + AOFF_WHY, (const float*)d_in[9], out);

  hlast_kernel<<<(BATCH * HID + 255) / 256, 256, 0, stream>>>(h0p, h1p, out);
}